// Round 6
// baseline (77.122 us; speedup 1.0000x reference)
//
#include <hip/hip_runtime.h>

// Euler characteristic curve (ECC) of V-construction cubical complex.
// x: [64,3,224,224] fp32 in [0,1). Out: [64,96] fp32 = per-(b,c) ECC over
// tseq = linspace(0,1,32); out[img*32+t], img = b*3+c.
//
// Cell->bin: bin(f) = ceil(31*f); monotonic so bin(max) = max(bin).
// Net-update formulation (one atomic slot per pixel per family):
//   pair1 (vertex/h-edge) at pixel k, d_k = [B_{k+1}>B_k]:  @B_k: d_k - d_{k-1}
//   pair2 (v-edge/square) along M_k = max(B_k,C_k), e_k = [M_{k+1}>M_k]:
//                                                           @M_k: e_{k-1} - e_k
// Sentinels: RIGHT neighbor of col 223 -> bin 64 (always-true). LEFT neighbor
// of col 0 -> bin 63 (always >=). Bottom row (r==H-1) skips pair2.
// Math verified absmax=0 (R7..R13).
//
// Evidence so far: single-pass kernel = 17.4us = 6.6us issue-bound compute
// (R11: VALUBusy 75%) + ~11us exposed HBM time at an effective 2.4 TB/s.
// R12 (bulk VGPR prefetch across barrier) = vmcnt(0) drain, -23us. R13
// (two chains + staged VGPR loads) = null: at the (256,6) VGPR cap the
// allocator re-serializes in-flight loads (R9's VGPR=28 shows the trim).
// Conclusion: the VGPR path cannot hold depth>2. Ideal overlap floor =
// max(6.6 compute, 6.8 stream) + ramp ~= 9us.
//
// R14: depth-8 at ZERO register cost via global_load_lds (T3+T4). Each wave
// issues all 8 row loads as async global->LDS DMA (no dest VGPRs), then
// consumes rows from LDS behind counted s_waitcnt vmcnt(7..0) + 
// sched_barrier(0) (rule 18) -- never a full drain, no barrier between
// issue and use (hist init + barrier run BEFORE any load: R12 lesson).
// LDS dest is wave-uniform base + lane*16 = stage[s][r][lane*16B]:
// contiguous, matches the per-lane global addr (c==lane), readback
// ds_read_b128 at c*16 is the canonical conflict-free pattern (m97).
// Cost: +28.7KB stage -> 37.2KB/block -> 4 blocks/CU (16 waves): in-flight
// = 16 waves x 8 x 896B ~= 115KB/CU >> BW*latency -- HBM-saturating.
// Predicted: kernel 17.4 -> ~9-12us, dur_us 76.6 -> ~68-71.

#define H 224
#define W 224
#define STEPS 32
#define NBINS 33            // bin 32 (f==1.0 edge case) kept memory-safe, discarded
#define NCOL 64
#define BANDS 8
#define BAND_ROWS 28        // rows per block
#define SUB_ROWS 7          // rows per wave (4 waves per block)
#define NTHR 256

// Counted vmcnt wait + scheduler fence (rule 18: keep dependent ds_read
// below the wait).
#define VMWAIT(N) do { asm volatile("s_waitcnt vmcnt(" #N ")" ::: "memory"); \
                       __builtin_amdgcn_sched_barrier(0); } while (0)

typedef __attribute__((address_space(3))) void       lds_void_t;
typedef const __attribute__((address_space(1))) void glb_void_t;

__device__ __forceinline__ int bin_of(float f) {
    // ceil(31*f) for f in [0,1): fma then trunc. 0.99999994f = 1-2^-24.
    return (int)fmaf(f, 31.0f, 0.99999994f);
}

struct BinState {
    int B0, B1, B2, B3, Bn, Bp;
};

__device__ __forceinline__ void init_state(BinState& S, float4 F,
                                           bool lastc, bool firstc)
{
    S.B0 = bin_of(F.x); S.B1 = bin_of(F.y);
    S.B2 = bin_of(F.z); S.B3 = bin_of(F.w);
    int t;
    t = __shfl_down(S.B0, 1); S.Bn = lastc  ? 64 : t;  // right: always-greater
    t = __shfl_up  (S.B3, 1); S.Bp = firstc ? 63 : t;  // left: never-smaller
}

// pair1: net vertex/h-edge updates at the 4 own pixels (unpredicated ds_add).
__device__ __forceinline__ void pair1_update(int* __restrict__ lhc,
                                             const BinState& S)
{
    int dm = (S.B0 > S.Bp) ? 1 : 0;
    int d0 = (S.B1 > S.B0) ? 1 : 0;
    int d1 = (S.B2 > S.B1) ? 1 : 0;
    int d2 = (S.B3 > S.B2) ? 1 : 0;
    int d3 = (S.Bn > S.B3) ? 1 : 0;
    atomicAdd(&lhc[S.B0 << 6], d0 - dm);
    atomicAdd(&lhc[S.B1 << 6], d1 - d0);
    atomicAdd(&lhc[S.B2 << 6], d2 - d1);
    atomicAdd(&lhc[S.B3 << 6], d3 - d2);
}

// pair2: net v-edge/square updates along M = max(B, C); rolls S <- C bins.
__device__ __forceinline__ void pair2_update_roll(int* __restrict__ lhc,
                                                  BinState& S, float4 G,
                                                  bool lastc, bool firstc)
{
    int C0 = bin_of(G.x), C1 = bin_of(G.y), C2 = bin_of(G.z), C3 = bin_of(G.w);
    int t;
    t = __shfl_down(C0, 1); int Cn = lastc  ? 64 : t;
    t = __shfl_up  (C3, 1); int Cp = firstc ? 63 : t;

    int M0 = max(S.B0, C0), M1 = max(S.B1, C1),
        M2 = max(S.B2, C2), M3 = max(S.B3, C3);
    int Mn = max(S.Bn, Cn), Mp = max(S.Bp, Cp);
    int em = (M0 > Mp) ? 1 : 0;
    int e0 = (M1 > M0) ? 1 : 0;
    int e1 = (M2 > M1) ? 1 : 0;
    int e2 = (M3 > M2) ? 1 : 0;
    int e3 = (Mn > M3) ? 1 : 0;
    atomicAdd(&lhc[M0 << 6], em - e0);
    atomicAdd(&lhc[M1 << 6], e0 - e1);
    atomicAdd(&lhc[M2 << 6], e1 - e2);
    atomicAdd(&lhc[M3 << 6], e2 - e3);

    S.B0 = C0; S.B1 = C1; S.B2 = C2; S.B3 = C3; S.Bn = Cn; S.Bp = Cp;
}

__global__ __launch_bounds__(NTHR, 4) void ecc_fused_kernel(
        const float* __restrict__ x, float* __restrict__ out)
{
    // stage[s][r]: wave s's row r, laid out lane*16B (global_load_lds order).
    __shared__ float stage[4][8][W];     // 28672 B
    __shared__ int lh[NBINS * NCOL];     // 8448 B; addr (bin*64+c)*4 -> 2-way bank aliasing (free)
    __shared__ int bins[STEPS];

    const int tid  = threadIdx.x;

    // Histogram init FIRST: the barrier fires with nothing in flight, so
    // the async loads below never meet a vmcnt(0) drain (R12 lesson).
    for (int i = tid; i < NBINS * NCOL; i += NTHR) lh[i] = 0;
    __syncthreads();

    const int band = blockIdx.x & (BANDS - 1);
    const int img  = blockIdx.x / BANDS;          // 0..191
    const float* __restrict__ p = x + (size_t)img * (H * W);

    const int c = tid & 63;      // column group: cols 4c..4c+3 (active c<56); c==lane
    const int s = tid >> 6;      // sub-band id == wave id (rows uniform per wave)
    const int r0 = band * BAND_ROWS + s * SUB_ROWS;

    if (c < 56) {
        const bool lastc    = (c == 55);
        const bool firstc   = (c == 0);
        const bool interior = (r0 != H - SUB_ROWS);
        int* __restrict__ lhc = lh + c;

        // --- Issue all 8 row loads as async global->LDS DMA (depth 8,
        // zero VGPR cost). Per-lane global src p + r*W + 16c bytes; LDS
        // dest wave-uniform &stage[s][r][0], HW scatters lane l -> +16l.
        const float* __restrict__ base = p + (size_t)r0 * W + (c << 2);
        {
            #pragma unroll
            for (int r = 0; r < 7; ++r) {
                __builtin_amdgcn_global_load_lds(
                    (glb_void_t*)(base + r * W),
                    (lds_void_t*)&stage[s][r][0], 16, 0, 0);
            }
            // Row 7: clamp for the boundary wave (value never consumed
            // there; load kept so vmcnt counts stay uniform).
            const int r7 = interior ? 7 : 6;
            __builtin_amdgcn_global_load_lds(
                (glb_void_t*)(base + r7 * W),
                (lds_void_t*)&stage[s][7][0], 16, 0, 0);
        }

        // --- Consume behind counted waits: row r ready at vmcnt(7-r). ---
        BinState S;
        VMWAIT(6);   // rows 0,1 landed
        float4 F0 = *(const float4*)&stage[s][0][c << 2];
        init_state(S, F0, lastc, firstc);
        pair1_update(lhc, S);
        {
            float4 G = *(const float4*)&stage[s][1][c << 2];
            pair2_update_roll(lhc, S, G, lastc, firstc);
            pair1_update(lhc, S);
        }
        VMWAIT(5);
        {
            float4 G = *(const float4*)&stage[s][2][c << 2];
            pair2_update_roll(lhc, S, G, lastc, firstc);
            pair1_update(lhc, S);
        }
        VMWAIT(4);
        {
            float4 G = *(const float4*)&stage[s][3][c << 2];
            pair2_update_roll(lhc, S, G, lastc, firstc);
            pair1_update(lhc, S);
        }
        VMWAIT(3);
        {
            float4 G = *(const float4*)&stage[s][4][c << 2];
            pair2_update_roll(lhc, S, G, lastc, firstc);
            pair1_update(lhc, S);
        }
        VMWAIT(2);
        {
            float4 G = *(const float4*)&stage[s][5][c << 2];
            pair2_update_roll(lhc, S, G, lastc, firstc);
            pair1_update(lhc, S);
        }
        VMWAIT(1);
        {
            float4 G = *(const float4*)&stage[s][6][c << 2];
            pair2_update_roll(lhc, S, G, lastc, firstc);
            pair1_update(lhc, S);
        }
        if (interior) {
            VMWAIT(0);
            float4 G = *(const float4*)&stage[s][7][c << 2];
            pair2_update_roll(lhc, S, G, lastc, firstc);
        }
        // Boundary wave (band 7, sub-band 3): bottom row has no row below;
        // its row-7 load drains at the __syncthreads below.
    }
    __syncthreads();

    // Reduce 64 columns -> 32 bin sums (bin 32, if ever hit, discarded).
    // tid = b*8+g: 8-lane groups are 8-aligned, shfl_xor 1/2/4 stays in-group.
    const int b = tid >> 3;              // 0..31
    const int g = tid & 7;
    const int4* rowp = (const int4*)(lh + (b << 6) + (g << 3));
    int4 u0 = rowp[0], u1 = rowp[1];
    int sum = u0.x + u0.y + u0.z + u0.w + u1.x + u1.y + u1.z + u1.w;
    sum += __shfl_xor(sum, 1);
    sum += __shfl_xor(sum, 2);
    sum += __shfl_xor(sum, 4);
    if (g == 0) bins[b] = sum;
    __syncthreads();

    // Wave 0, lanes 0..31: inclusive prefix over bins, then one float
    // atomicAdd per bin into d_out (8 band blocks accumulate per image).
    if (tid < STEPS) {
        int v = bins[tid];
        #pragma unroll
        for (int off = 1; off < STEPS; off <<= 1) {
            int u = __shfl_up(v, off);
            if (tid >= off) v += u;
        }
        atomicAdd(&out[img * STEPS + tid], (float)v);
    }
}

extern "C" void kernel_launch(void* const* d_in, const int* in_sizes, int n_in,
                              void* d_out, int out_size, void* d_ws, size_t ws_size,
                              hipStream_t stream) {
    const float* x = (const float*)d_in[0];
    float* out = (float*)d_out;

    const int nimg = in_sizes[0] / (H * W);      // 192

    dim3 grid(nimg * BANDS);
    ecc_fused_kernel<<<grid, NTHR, 0, stream>>>(x, out);
}

// Round 8
// 74.566 us; speedup vs baseline: 1.0343x; 1.0343x over previous
//
#include <hip/hip_runtime.h>

// Euler characteristic curve (ECC) of V-construction cubical complex.
// x: [64,3,224,224] fp32 in [0,1). Out: [64,96] fp32 = per-(b,c) ECC over
// tseq = linspace(0,1,32); out[img*32+t], img = b*3+c.
//
// Cell->bin: bin(f) = ceil(31*f); monotonic so bin(max) = max(bin).
// Net-update formulation (one atomic slot per pixel per family):
//   pair1 (vertex/h-edge) at pixel k, d_k = [B_{k+1}>B_k]:  @B_k: d_k - d_{k-1}
//   pair2 (v-edge/square) along M_k = max(B_k,C_k), e_k = [M_{k+1}>M_k]:
//                                                           @M_k: e_{k-1} - e_k
// Sentinels: RIGHT neighbor of col 223 -> bin 64 (always-true). LEFT neighbor
// of col 0 -> bin 63 (always >=). Bottom row (r==H-1) skips pair2.
// Math verified absmax=0 (R7..R14).
//
// Evidence ledger: single-pass kernel = 16.2us; warm compute = 6.6us
// (R11, VALUBusy 75%); clean stream = 6.7us (42MB @ 6.3TB/s). Four
// mechanistically distinct pipelining attacks on the ~9.6us surplus all
// null/regressed (R12 VGPR bulk, R13 staged VGPR, R14 depth-8
// global_load_lds with counted vmcnt; R10 substrate swap). Conclusion:
// the surplus is NOT overlappable latency. Remaining suspect: per-block
// FIXED cost x1536 instances (init+barrier, reduce, scan, 8-way-contended
// out[] atomics, ramp/drain) — corroborated by R11's 45% occupancy
// (structural is 75%: ramp/tail dips).
//
// R15 (resubmit; R15 bench was an infra failure "container failed twice",
// no signal — same transient signature as R1, which passed on resubmit;
// kernel re-audited: bounds, LDS, launch config all safe): ONE variable
// vs R9 (best, 75.4): block granularity. 512-thread blocks (8 waves),
// 4 bands/image of 56 rows; wave s owns rows band*56+s*7 .. +6. Loop
// body, hist substrate, reduction, scan: byte-identical to R9. Effects:
// F instances 1536->768, out-atomic contention 8->4, occupancy unchanged
// (768 blocks = 3/CU x 8 waves = 24 waves/CU, same as 6 x 4). Cross-wave
// hist atomic contention is free (R9==R10 evidence).
// Predicted: dur 75.4 -> 72-74 if F-theory right; null => declare
// roofline (16.2 ~= 6.6 compute + 6.7 stream + ~3 fixed, no overlap,
// structural).

#define H 224
#define W 224
#define STEPS 32
#define NBINS 33            // bin 32 (f==1.0 edge case) kept memory-safe, discarded
#define NCOL 64
#define BANDS 4
#define BAND_ROWS 56        // rows per block
#define SUB_ROWS 7          // rows per wave (8 waves per block)
#define NTHR 512

__device__ __forceinline__ int bin_of(float f) {
    // ceil(31*f) for f in [0,1): fma then trunc. 0.99999994f = 1-2^-24.
    return (int)fmaf(f, 31.0f, 0.99999994f);
}

struct BinState {
    int B0, B1, B2, B3, Bn, Bp;
};

// pair1: net vertex/h-edge updates at the 4 own pixels (unpredicated ds_add).
__device__ __forceinline__ void pair1_update(int* __restrict__ lhc,
                                             const BinState& S)
{
    int dm = (S.B0 > S.Bp) ? 1 : 0;
    int d0 = (S.B1 > S.B0) ? 1 : 0;
    int d1 = (S.B2 > S.B1) ? 1 : 0;
    int d2 = (S.B3 > S.B2) ? 1 : 0;
    int d3 = (S.Bn > S.B3) ? 1 : 0;
    atomicAdd(&lhc[S.B0 << 6], d0 - dm);
    atomicAdd(&lhc[S.B1 << 6], d1 - d0);
    atomicAdd(&lhc[S.B2 << 6], d2 - d1);
    atomicAdd(&lhc[S.B3 << 6], d3 - d2);
}

// pair2: net v-edge/square updates along M = max(B, C); rolls S <- C bins.
__device__ __forceinline__ void pair2_update_roll(int* __restrict__ lhc,
                                                  BinState& S, float4 G,
                                                  bool lastc, bool firstc)
{
    int C0 = bin_of(G.x), C1 = bin_of(G.y), C2 = bin_of(G.z), C3 = bin_of(G.w);
    int t;
    t = __shfl_down(C0, 1); int Cn = lastc  ? 64 : t;
    t = __shfl_up  (C3, 1); int Cp = firstc ? 63 : t;

    int M0 = max(S.B0, C0), M1 = max(S.B1, C1),
        M2 = max(S.B2, C2), M3 = max(S.B3, C3);
    int Mn = max(S.Bn, Cn), Mp = max(S.Bp, Cp);
    int em = (M0 > Mp) ? 1 : 0;
    int e0 = (M1 > M0) ? 1 : 0;
    int e1 = (M2 > M1) ? 1 : 0;
    int e2 = (M3 > M2) ? 1 : 0;
    int e3 = (Mn > M3) ? 1 : 0;
    atomicAdd(&lhc[M0 << 6], em - e0);
    atomicAdd(&lhc[M1 << 6], e0 - e1);
    atomicAdd(&lhc[M2 << 6], e1 - e2);
    atomicAdd(&lhc[M3 << 6], e2 - e3);

    S.B0 = C0; S.B1 = C1; S.B2 = C2; S.B3 = C3; S.Bn = Cn; S.Bp = Cp;
}

__global__ __launch_bounds__(NTHR, 6) void ecc_fused_kernel(
        const float* __restrict__ x, float* __restrict__ out)
{
    // Shared across the block's 8 waves. Update addr = (bin*64 + c)*4:
    // bank = c%32 -> 2-way wave aliasing (free, m136); cross-wave atomic
    // contention measured free (R9 atomics == R10 private-slab RMW).
    __shared__ int lh[NBINS * NCOL];     // 8448 B
    __shared__ int bins[STEPS];

    const int tid = threadIdx.x;
    for (int i = tid; i < NBINS * NCOL; i += NTHR) lh[i] = 0;
    __syncthreads();

    const int band = blockIdx.x & (BANDS - 1);
    const int img  = blockIdx.x / BANDS;          // 0..191
    const float* __restrict__ p = x + (size_t)img * (H * W);

    const int c = tid & 63;      // column group: cols 4c..4c+3 (active c<56); c==lane
    const int s = tid >> 6;      // sub-band id == wave id 0..7 (rows uniform per wave)

    if (c < 56) {
        const bool lastc  = (c == 55);
        const bool firstc = (c == 0);
        const int  r0 = band * BAND_ROWS + s * SUB_ROWS;   // 0..217 step 7
        int* __restrict__ lhc = lh + c;

        const float* __restrict__ row = p + r0 * W + (c << 2);
        float4 F = *(const float4*)row;
        BinState S;
        S.B0 = bin_of(F.x); S.B1 = bin_of(F.y);
        S.B2 = bin_of(F.z); S.B3 = bin_of(F.w);
        int t;
        t = __shfl_down(S.B0, 1); S.Bn = lastc  ? 64 : t;  // right: always-greater
        t = __shfl_up  (S.B3, 1); S.Bp = firstc ? 63 : t;  // left: never-smaller

        if (r0 != H - SUB_ROWS) {
            // Interior wave: rows r0..r0+6 all have a row below. Branch-free
            // unrolled body -> compiler pipelines the next-row loads (R9).
            #pragma unroll
            for (int k = 0; k < SUB_ROWS; ++k) {
                pair1_update(lhc, S);
                float4 G = *(const float4*)(row + W);
                pair2_update_roll(lhc, S, G, lastc, firstc);
                row += W;
            }
        } else {
            // The single boundary wave (band 3, sub-band 7): 6 full rows,
            // then pair1-only on the bottom row (r == H-1).
            #pragma unroll
            for (int k = 0; k < SUB_ROWS - 1; ++k) {
                pair1_update(lhc, S);
                float4 G = *(const float4*)(row + W);
                pair2_update_roll(lhc, S, G, lastc, firstc);
                row += W;
            }
            pair1_update(lhc, S);
        }
    }
    __syncthreads();

    // Reduce 64 columns -> 32 bin sums (bin 32, if ever hit, discarded).
    // First 256 threads only; tid = b*8+g: 8-lane groups are 8-aligned,
    // shfl_xor 1/2/4 stays in-group.
    if (tid < 256) {
        const int b = tid >> 3;              // 0..31
        const int g = tid & 7;
        const int4* rowp = (const int4*)(lh + (b << 6) + (g << 3));
        int4 u0 = rowp[0], u1 = rowp[1];
        int sum = u0.x + u0.y + u0.z + u0.w + u1.x + u1.y + u1.z + u1.w;
        sum += __shfl_xor(sum, 1);
        sum += __shfl_xor(sum, 2);
        sum += __shfl_xor(sum, 4);
        if (g == 0) bins[b] = sum;
    }
    __syncthreads();

    // Wave 0, lanes 0..31: inclusive prefix over bins, then one float
    // atomicAdd per bin into d_out (4 band blocks accumulate per image).
    if (tid < STEPS) {
        int v = bins[tid];
        #pragma unroll
        for (int off = 1; off < STEPS; off <<= 1) {
            int u = __shfl_up(v, off);
            if (tid >= off) v += u;
        }
        atomicAdd(&out[img * STEPS + tid], (float)v);
    }
}

extern "C" void kernel_launch(void* const* d_in, const int* in_sizes, int n_in,
                              void* d_out, int out_size, void* d_ws, size_t ws_size,
                              hipStream_t stream) {
    const float* x = (const float*)d_in[0];
    float* out = (float*)d_out;

    const int nimg = in_sizes[0] / (H * W);      // 192

    dim3 grid(nimg * BANDS);                      // 768 blocks of 512 threads
    ecc_fused_kernel<<<grid, NTHR, 0, stream>>>(x, out);
}